// Round 9
// baseline (202.328 us; speedup 1.0000x reference)
//
#include <hip/hip_runtime.h>
#include <stdint.h>

#define NB 16
#define NC 512
#define NS 1024
#define NR 32

typedef unsigned short u16;
typedef unsigned int u32;

typedef __attribute__((ext_vector_type(8))) short short8;
typedef __attribute__((ext_vector_type(4))) float f32x4;

__device__ __forceinline__ float bf2f(u16 u) {
    union { u32 i; float f; } c; c.i = ((u32)u) << 16; return c.f;
}
__device__ __forceinline__ u16 f2bf(float f) {
    union { float f; u32 i; } c; c.f = f;
    u32 r = (c.i + 0x7FFFu + ((c.i >> 16) & 1u)) >> 16;
    return (u16)r;
}
__device__ __forceinline__ float sigm(float x) {
    return 1.0f / (1.0f + __expf(-x));
}

#define GLD16(gp, lp)                                                      \
    __builtin_amdgcn_global_load_lds(                                      \
        (const __attribute__((address_space(1))) u32*)(gp),                \
        (__attribute__((address_space(3))) u32*)(lp), 16, 0, 0)

// ---- L1: spatial mean (0..8191) + dw cvt (8192..10239) + a-recovery (10240)
// a[i][y] = sum_x gus[(i*32), y, x]  (row sums recover the separable factor:
// gus[(i,k),y,x] = a[i,y]*a[k,x] with rows of a normalized to 1).
__global__ void k_pre(const float* __restrict__ x, float* __restrict__ sm,
                      const float* __restrict__ dw, u16* __restrict__ dwb,
                      const float* __restrict__ g, float* __restrict__ abuf) {
    const int t = threadIdx.x;                  // 256
    if (blockIdx.x < NB * NC) {
        const int row = blockIdx.x;             // b*NC + c
        const float4* xr = (const float4*)(x + (long)row * NS);
        float4 v = xr[t];
        float p = v.x + v.y + v.z + v.w;
        for (int off = 32; off; off >>= 1) p += __shfl_down(p, off);
        __shared__ __align__(16) float red[4];
        if ((t & 63) == 0) red[t >> 6] = p;
        __syncthreads();
        if (t == 0) sm[row] = (red[0] + red[1] + red[2] + red[3]) * (1.0f / 1024.0f);
    } else if (blockIdx.x < NB * NC + 2048) {
        const int i = (blockIdx.x - NB * NC) * 256 + t;   // 524288 exactly
        dwb[i] = f2bf(dw[i]);
    } else {
        // a-recovery: 1024 (i,y) pairs, 4 per thread
#pragma unroll
        for (int it = 0; it < 4; ++it) {
            int idx = it * 256 + t;
            int i = idx >> 5, y = idx & 31;
            const float* row = g + (long)(i * 32) * 1024 + y * 32;
            float s = 0.f;
#pragma unroll
            for (int xx = 0; xx < 32; ++xx) s += row[xx];
            abuf[idx] = s;                      // a_n layout [i][y]
        }
    }
}

// ---- L2: SE MLP: y = sigmoid(relu(s W1^T + b1) W2^T + b2) ---------------
__global__ void k_se(const float* __restrict__ sm, const float* __restrict__ w1,
                     const float* __restrict__ b1, const float* __restrict__ w2,
                     const float* __restrict__ b2, float* __restrict__ y) {
    const int b = blockIdx.x;
    __shared__ __align__(16) float s_s[NC];
    __shared__ __align__(16) float s_y1[NR];
    const int t = threadIdx.x;                  // 256
    s_s[t] = sm[b * NC + t];
    s_s[t + 256] = sm[b * NC + t + 256];
    __syncthreads();
    {
        const int r = t >> 3, sub = t & 7;
        const float4* wr = (const float4*)(w1 + r * NC + sub * 64);
        const float4* sv = (const float4*)(s_s + sub * 64);
        float acc = 0.f;
#pragma unroll
        for (int i = 0; i < 16; ++i) {
            float4 wv = wr[i];
            float4 s4 = sv[i];
            acc += wv.x * s4.x + wv.y * s4.y + wv.z * s4.z + wv.w * s4.w;
        }
        acc += __shfl_down(acc, 4);
        acc += __shfl_down(acc, 2);
        acc += __shfl_down(acc, 1);
        if (sub == 0) s_y1[r] = fmaxf(acc + b1[r], 0.0f);
    }
    __syncthreads();
    for (int i = 0; i < 2; ++i) {
        int c = t + i * 256;
        float acc = b2[c];
#pragma unroll
        for (int r = 0; r < NR; ++r) acc += s_y1[r] * w2[c * NR + r];
        y[b * NC + c] = 1.0f / (1.0f + expf(-acc));
    }
}

// ---- L3: out32 = x*y -> bf16 [c,s] (o32), [s,c] (o32t), sigmoid [s,c] ---
__global__ void k_scale(const float* __restrict__ x, const float* __restrict__ y,
                        u16* __restrict__ o32, u16* __restrict__ o32t,
                        u16* __restrict__ sig_t) {
    const int b = blockIdx.z;
    const int c0 = blockIdx.y * 32;
    const int s0 = blockIdx.x * 32;
    const int tx = threadIdx.x & 31, ty = threadIdx.x >> 5;
    __shared__ float tile[32][33];
    const float* xb = x + (long)b * NC * NS;
#pragma unroll
    for (int it = 0; it < 4; ++it) {
        int c = c0 + ty + it * 8;
        float v = xb[(long)c * NS + s0 + tx] * y[b * NC + c];
        tile[ty + it * 8][tx] = v;
        o32[((long)b * NC + c) * NS + s0 + tx] = f2bf(v);
    }
    __syncthreads();
#pragma unroll
    for (int it = 0; it < 4; ++it) {
        int sr = ty + it * 8;
        float tv = tile[tx][sr];
        long idx = ((long)b * NS + (s0 + sr)) * NC + c0 + tx;
        o32t[idx] = f2bf(tv);
        sig_t[idx] = f2bf(sigm(tv));
    }
}

// ---- L4: patch attention, 8 x-positions per block, 512 threads ----------
// halo = 3 rows x 10 x = 30 pairs. OOB entries are 0 (pad after sigmoid).
__global__ __launch_bounds__(512)
void k_attn(const u16* __restrict__ sig_t, const u16* __restrict__ o32t,
            u16* __restrict__ g2) {
    const int wave = threadIdx.x >> 6, lane = threadIdx.x & 63;
    const int tid = threadIdx.x;
    const int bx = blockIdx.x;                   // 128 blocks/batch: 4 per row
    const int b = blockIdx.y;
    const int y0 = bx >> 2;
    const int xbase = (bx & 3) * 8;
    const long base = (long)b * NS * NC;
    __shared__ __align__(16) u16 smem[2 * 30 * NC];   // sig: 0..29, raw: 30..59

#pragma unroll
    for (int it = 0; it < 4; ++it) {
        int idx = it * 512 + tid;                 // 1920 chunks total
        if (idx < 30 * 64) {
            int pair = idx >> 6;                  // 0..29, wave-uniform
            int ch0 = (idx & 63) * 8;
            int prow = pair / 10;
            int pxc = pair - prow * 10;
            int yy = y0 + prow - 1;
            int xx = xbase + pxc - 1;
            short8 rv = (short8){0, 0, 0, 0, 0, 0, 0, 0};
            short8 sv = (short8){0, 0, 0, 0, 0, 0, 0, 0};
            if (yy >= 0 && yy < 32 && xx >= 0 && xx < 32) {
                long roff = base + (long)(yy * 32 + xx) * NC + ch0;
                rv = *(const short8*)&o32t[roff];
                sv = *(const short8*)&sig_t[roff];
            }
            *(short8*)&smem[pair * NC + ch0] = sv;
            *(short8*)&smem[(30 + pair) * NC + ch0] = rv;
        }
    }
    __syncthreads();

    const int coff = lane * 8;
    short8 csv = *(const short8*)&smem[(11 + wave) * NC + coff];   // own sig
    float sc[8];
#pragma unroll
    for (int j = 0; j < 8; ++j) sc[j] = bf2f((u16)csv[j]);

    float part[9];
#pragma unroll
    for (int k = 0; k < 9; ++k) {
        int pair = (k / 3) * 10 + wave + k % 3;
        short8 sv = *(const short8*)&smem[pair * NC + coff];
        float p = 0.f;
#pragma unroll
        for (int j = 0; j < 8; ++j) p += sc[j] * bf2f((u16)sv[j]);
        part[k] = p;
    }
#pragma unroll
    for (int k = 0; k < 9; ++k)
        for (int off = 32; off; off >>= 1) part[k] += __shfl_down(part[k], off);

    if (lane == 0) {
        float mx = -1e30f;
#pragma unroll
        for (int k = 0; k < 9; ++k) { part[k] *= (1.0f / 512.0f); mx = fmaxf(mx, part[k]); }
        float sum = 0.f;
#pragma unroll
        for (int k = 0; k < 9; ++k) { part[k] = __expf(part[k] - mx); sum += part[k]; }
        float inv = 1.0f / sum;
#pragma unroll
        for (int k = 0; k < 9; ++k) part[k] *= inv;
    }
    float g[8] = {0.f, 0.f, 0.f, 0.f, 0.f, 0.f, 0.f, 0.f};
#pragma unroll
    for (int k = 0; k < 9; ++k) {
        float a = __shfl(part[k], 0);
        int pair = (k / 3) * 10 + wave + k % 3;
        short8 rv = *(const short8*)&smem[(30 + pair) * NC + coff];
#pragma unroll
        for (int j = 0; j < 8; ++j) g[j] += a * bf2f((u16)rv[j]);
    }
    short8 ov;
#pragma unroll
    for (int j = 0; j < 8; ++j) ov[j] = (short)f2bf(g[j]);
    const int s = y0 * 32 + xbase + wave;
    *(short8*)&g2[base + (long)s * NC + coff] = ov;
}

// ---- L5: build Bcat[b][band][r=c][k], rows of 1024:
//   cols   0..511  (blocks 0..63):  separable gus_out — Bcat[.][q][c][i] =
//       gus_out[b, p=2i+q, c], p=(i_p,k_p)=i_p*32+k_p, i=i_p*16+(k_p>>1), q=k_p&1
//   cols 512..1023 (blocks 64..191): transpose of g2b — Bcat[.][q][c][512+j] =
//       g2b[b][2j+q][c]   (old k_tr2, retargeted to ldb=1024 rows)
__global__ __launch_bounds__(256)
void k_bcat(const u16* __restrict__ o32, const float* __restrict__ abuf,
            const u16* __restrict__ g2, u16* __restrict__ bc) {
    const int b = blockIdx.y;
    const int t = threadIdx.x;
    __shared__ __align__(16) float a_n[1024];     // a[i][y]
    __shared__ __align__(16) float a_t[1024];     // a[k,x] stored [x][k]
    __shared__ __align__(16) u16 orow[8][1024];   // 16 KB
    __shared__ __align__(16) u16 tile[64 * 64];   // 8 KB (tr2 half)
    if (blockIdx.x < 64) {
        const int c0 = blockIdx.x * 8;
#pragma unroll
        for (int it = 0; it < 4; ++it) {
            int idx = it * 256 + t;
            float v = abuf[idx];
            a_n[idx] = v;
            a_t[(idx & 31) * 32 + (idx >> 5)] = v;
        }
#pragma unroll
        for (int it = 0; it < 4; ++it) {
            int cc = it * 256 + t;
            int cl = cc >> 7, off = (cc & 127) * 8;
            *(short8*)&orow[cl][off] =
                *(const short8*)&o32[((long)b * NC + c0 + cl) * NS + off];
        }
        __syncthreads();
        const int cl = t >> 5, k = t & 31;        // 8 c-rows x 32 k-columns
        float tc[32];                             // T[y, k] = sum_x a[k,x] O[y,x]
#pragma unroll
        for (int yy = 0; yy < 32; ++yy) {
            float s = 0.f;
#pragma unroll
            for (int xx = 0; xx < 32; ++xx)
                s += a_t[xx * 32 + k] * bf2f(orow[cl][yy * 32 + xx]);
            tc[yy] = s;
        }
        u16* dst = bc + (long)b * 1048576 + (long)(k & 1) * 524288 +
                   (long)(c0 + cl) * 1024 + (k >> 1);
#pragma unroll
        for (int ip = 0; ip < 32; ++ip) {         // G[p=(ip,k)] = sum_y a[ip,y] T[y,k]
            float gv = 0.f;
#pragma unroll
            for (int yy = 0; yy < 32; ++yy) gv += a_n[ip * 32 + yy] * tc[yy];
            dst[ip * 16] = f2bf(gv);              // 16 lanes cover a 32B sector
        }
    } else {
        const int bx2 = blockIdx.x - 64;          // 0..127
        const int c0 = (bx2 & 7) * 64;
        const int j0 = ((bx2 >> 3) & 7) * 64;
        const int q = bx2 >> 6;
        const u16* src = g2 + (long)b * 524288 + (long)(2 * j0 + q) * 512 + c0;
#pragma unroll
        for (int it = 0; it < 2; ++it) {
            int c = it * 256 + t;
            int jl = c >> 3, sg = c & 7;
            short8 v = *(const short8*)&src[(long)jl * 1024 + sg * 8];
            int slot = sg ^ ((jl >> 3) & 7);
            *(short8*)&tile[jl * 64 + slot * 8] = v;
        }
        __syncthreads();
#pragma unroll
        for (int it = 0; it < 2; ++it) {
            int c = it * 256 + t;
            int cl = c >> 3, jg = c & 7;
            const int gcs = cl >> 3, co = cl & 7;
            short8 v;
#pragma unroll
            for (int jj = 0; jj < 8; ++jj) {
                int j = jg * 8 + jj;
                int slot = gcs ^ jg;               // (j>>3)&7 == jg
                v[jj] = (short)tile[j * 64 + slot * 8 + co];
            }
            *(short8*)&bc[(long)b * 1048576 + (long)q * 524288 +
                          (long)(c0 + cl) * 1024 + 512 + j0 + jg * 8] = v;
        }
    }
}

// ---- L6: Z[o, band*512+r] = sum_{k<1024} dwb[o,k] * Bcat[b][band][r][k]
// uniform K=1024, BK=128, 128(m) x 64(n) tile, grid 1024 blocks.
#define MFMA_TILE_STEP(As, Bs, NW)                                                  \
    {                                                                               \
        _Pragma("unroll")                                                           \
        for (int kk = 0; kk < 128; kk += 32) {                                      \
            const int gq = (kk >> 3) + (lane >> 4);                                 \
            const int slot = gq ^ (lane & 15);                                      \
            short8 af[4], bfr[NW];                                                  \
            _Pragma("unroll")                                                       \
            for (int i = 0; i < 4; ++i)                                             \
                af[i] = *(const short8*)&As[(wm + i * 16 + (lane & 15)) * 128 + slot * 8]; \
            _Pragma("unroll")                                                       \
            for (int j = 0; j < NW; ++j)                                            \
                bfr[j] = *(const short8*)&Bs[(wn + j * 16 + (lane & 15)) * 128 + slot * 8]; \
            _Pragma("unroll")                                                       \
            for (int i = 0; i < 4; ++i)                                             \
                _Pragma("unroll")                                                   \
                for (int j = 0; j < NW; ++j)                                        \
                    acc[i][j] = __builtin_amdgcn_mfma_f32_16x16x32_bf16(af[i], bfr[j], acc[i][j], 0, 0, 0); \
        }                                                                           \
    }

__global__ __launch_bounds__(256)
void k_zgemm(const u16* __restrict__ dwb, const u16* __restrict__ bc,
             u16* __restrict__ Z) {
    const int b = blockIdx.z;
    const int band = blockIdx.y & 1;
    const int m0 = (blockIdx.y >> 1) * 128;      // o
    const int n0 = blockIdx.x * 64;              // r
    __shared__ __align__(16) u16 As[128 * 128];  // 32 KB
    __shared__ __align__(16) u16 Bs[64 * 128];   // 16 KB
    const int tid = threadIdx.x;
    const int lane = tid & 63, wave = tid >> 6;
    const int wm = (wave >> 1) * 64, wn = (wave & 1) * 32;
    f32x4 acc[4][2];
#pragma unroll
    for (int i = 0; i < 4; ++i)
#pragma unroll
        for (int j = 0; j < 2; ++j) acc[i][j] = (f32x4){0.f, 0.f, 0.f, 0.f};

    const u16* A = dwb + (long)m0 * 1024;
    const u16* B = bc + (long)b * 1048576 + (long)band * 524288 + (long)n0 * 1024;

    for (int k0 = 0; k0 < 1024; k0 += 128) {
#pragma unroll
        for (int r = 0; r < 8; ++r) {
            const int c = r * 256 + tid;
            const int srow = c >> 4;
            const int sg = ((c & 15) ^ (srow & 15)) * 8;
            GLD16(A + (long)srow * 1024 + (k0 + sg), &As[c * 8]);
        }
#pragma unroll
        for (int r = 0; r < 4; ++r) {
            const int c = r * 256 + tid;
            const int srow = c >> 4;
            const int sg = ((c & 15) ^ (srow & 15)) * 8;
            GLD16(B + (long)srow * 1024 + (k0 + sg), &Bs[c * 8]);
        }
        __syncthreads();
        MFMA_TILE_STEP(As, Bs, 2);
        __syncthreads();
    }
    const int col = lane & 15, rq = (lane >> 4) * 4;
#pragma unroll
    for (int i = 0; i < 4; ++i)
#pragma unroll
        for (int j = 0; j < 2; ++j)
#pragma unroll
            for (int r = 0; r < 4; ++r) {
                int row = m0 + wm + i * 16 + rq + r;
                int ncol = n0 + wn + j * 16 + col;
                Z[((long)b * 512 + row) * 1024 + band * 512 + ncol] = f2bf(acc[i][j][r]);
            }
}

// ---- L7: InstanceNorm over s (1024) + LeakyReLU(0.2), bf16 in -----------
__global__ void k_norm(const u16* __restrict__ z, float* __restrict__ out) {
    const int row = blockIdx.x;
    const int t = threadIdx.x;
    uint2 u = ((const uint2*)(z + (long)row * NS))[t];
    float v0 = bf2f((u16)(u.x & 0xffffu)), v1 = bf2f((u16)(u.x >> 16));
    float v2 = bf2f((u16)(u.y & 0xffffu)), v3 = bf2f((u16)(u.y >> 16));
    float sm = v0 + v1 + v2 + v3;
    float sq = v0 * v0 + v1 * v1 + v2 * v2 + v3 * v3;
    for (int off = 32; off; off >>= 1) { sm += __shfl_down(sm, off); sq += __shfl_down(sq, off); }
    __shared__ __align__(16) float rs[4], rq2[4];
    if ((t & 63) == 0) { rs[t >> 6] = sm; rq2[t >> 6] = sq; }
    __syncthreads();
    float tot = rs[0] + rs[1] + rs[2] + rs[3];
    float totq = rq2[0] + rq2[1] + rq2[2] + rq2[3];
    float mu = tot * (1.0f / 1024.0f);
    float var = totq * (1.0f / 1024.0f) - mu * mu;
    float sc = rsqrtf(var + 1e-5f);
    float4 o;
    float a;
    a = (v0 - mu) * sc; o.x = (a >= 0.f) ? a : 0.2f * a;
    a = (v1 - mu) * sc; o.y = (a >= 0.f) ? a : 0.2f * a;
    a = (v2 - mu) * sc; o.z = (a >= 0.f) ? a : 0.2f * a;
    a = (v3 - mu) * sc; o.w = (a >= 0.f) ? a : 0.2f * a;
    ((float4*)(out + (long)row * NS))[t] = o;
}

extern "C" void kernel_launch(void* const* d_in, const int* in_sizes, int n_in,
                              void* d_out, int out_size, void* d_ws, size_t ws_size,
                              hipStream_t stream) {
    const float* x   = (const float*)d_in[0];
    const float* w1  = (const float*)d_in[1];
    const float* b1  = (const float*)d_in[2];
    const float* w2  = (const float*)d_in[3];
    const float* b2  = (const float*)d_in[4];
    const float* dw  = (const float*)d_in[5];
    const float* gus = (const float*)d_in[6];
    float* out = (float*)d_out;
    char* ws = (char*)d_ws;

    // layout (65.2 MB total, fits the proven >=70.3 MB workspace):
    //  head 1.2 MB | o32 16 | Bcat 32 | g2b 16
    //  o32t (16) + sig_t (16) overlay Bcat (dead once k_bcat starts)
    //  Z (16) overlays o32 (dead after k_bcat's go-half)
    float* sm_buf = (float*)(ws + 0);                    // 32 KB
    float* y_buf  = (float*)(ws + 32768);                // 32 KB
    float* a_buf  = (float*)(ws + 65536);                // 4 KB
    u16* dwbf     = (u16*)(ws + 131072);                 // 1 MB  [512][1024]
    u16* o32      = (u16*)(ws + 1179648);                // 16 MB [b][c][s]
    u16* Bcat     = (u16*)(ws + 17956864);               // 32 MB [b][2][512][1024]
    u16* o32t     = (u16*)(ws + 17956864);               // 16 MB (over Bcat lo)
    u16* sig_t    = (u16*)(ws + 34734080);               // 16 MB (over Bcat hi)
    u16* g2b      = (u16*)(ws + 51511296);               // 16 MB [b][p][c]
    u16* Z        = (u16*)(ws + 1179648);                // 16 MB (over o32)

    // L1: mean + dw cvt + a-recovery
    k_pre<<<dim3(NB * NC + 2048 + 1), dim3(256), 0, stream>>>(
        x, sm_buf, dw, dwbf, gus, a_buf);
    // L2: SE MLP
    k_se<<<dim3(NB), dim3(256), 0, stream>>>(sm_buf, w1, b1, w2, b2, y_buf);
    // L3: scale (o32, o32t, sig_t)
    k_scale<<<dim3(32, 16, NB), dim3(256), 0, stream>>>(x, y_buf, o32, o32t, sig_t);
    // L4: attn (reads o32t+sig_t, writes g2b; o32t/sig_t dead after)
    k_attn<<<dim3(128, NB), dim3(512), 0, stream>>>(sig_t, o32t, g2b);
    // L5: Bcat build — go-half (reads o32+a) + tr2-half (reads g2b)
    k_bcat<<<dim3(192, NB), dim3(256), 0, stream>>>(o32, a_buf, g2b, Bcat);
    // L6: uniform Z GEMM (K=1024); Z over o32 slot (dead)
    k_zgemm<<<dim3(8, 8, NB), dim3(256), 0, stream>>>(dwbf, Bcat, Z);
    // L7: instance norm + leaky relu
    k_norm<<<dim3(NB * NC), dim3(256), 0, stream>>>(Z, out);
}

// Round 10
// 185.242 us; speedup vs baseline: 1.0922x; 1.0922x over previous
//
#include <hip/hip_runtime.h>
#include <stdint.h>

#define NB 16
#define NC 512
#define NS 1024
#define NR 32

typedef unsigned short u16;
typedef unsigned int u32;

typedef __attribute__((ext_vector_type(8))) short short8;
typedef __attribute__((ext_vector_type(4))) float f32x4;

__device__ __forceinline__ float bf2f(u16 u) {
    union { u32 i; float f; } c; c.i = ((u32)u) << 16; return c.f;
}
__device__ __forceinline__ u16 f2bf(float f) {
    union { float f; u32 i; } c; c.f = f;
    u32 r = (c.i + 0x7FFFu + ((c.i >> 16) & 1u)) >> 16;
    return (u16)r;
}
__device__ __forceinline__ float sigm(float x) {
    return 1.0f / (1.0f + __expf(-x));
}

#define GLD16(gp, lp)                                                      \
    __builtin_amdgcn_global_load_lds(                                      \
        (const __attribute__((address_space(1))) u32*)(gp),                \
        (__attribute__((address_space(3))) u32*)(lp), 16, 0, 0)

// ---- launch 1: spatial mean (0..8191) + dw cvt (..10239) + gusT (..10495)
__global__ void k_pre(const float* __restrict__ x, float* __restrict__ sm,
                      const float* __restrict__ dw, u16* __restrict__ dwb,
                      const float* __restrict__ g, u16* __restrict__ gt) {
    __shared__ __align__(16) float shb[64 * 65];    // gusT tile; mean uses [0..3]
    const int t = threadIdx.x;                  // 256
    if (blockIdx.x < NB * NC) {
        const int row = blockIdx.x;             // b*NC + c
        const float4* xr = (const float4*)(x + (long)row * NS);
        float4 v = xr[t];
        float p = v.x + v.y + v.z + v.w;
        for (int off = 32; off; off >>= 1) p += __shfl_down(p, off);
        if ((t & 63) == 0) shb[t >> 6] = p;
        __syncthreads();
        if (t == 0) sm[row] = (shb[0] + shb[1] + shb[2] + shb[3]) * (1.0f / 1024.0f);
    } else if (blockIdx.x < NB * NC + 2048) {
        const int i = (blockIdx.x - NB * NC) * 256 + t;   // 524288 exactly
        dwb[i] = f2bf(dw[i]);
    } else {
        // gusT: gus fp32 [1024 p][1024 sp] -> gt[q][sp][i] = gus[2i+q][sp]
        const int gbx = blockIdx.x - (NB * NC + 2048);    // 0..255
        const int p0 = (gbx & 15) * 64;
        const int k0 = (gbx >> 4) * 64;
        float (*tile)[65] = (float(*)[65])shb;
#pragma unroll
        for (int it = 0; it < 4; ++it) {
            int c = it * 256 + t;          // 0..1023
            int row = c >> 4;              // p_loc
            int f4 = c & 15;
            float4 v = *(const float4*)&g[(long)(p0 + row) * 1024 + k0 + f4 * 4];
            tile[row][f4 * 4 + 0] = v.x; tile[row][f4 * 4 + 1] = v.y;
            tile[row][f4 * 4 + 2] = v.z; tile[row][f4 * 4 + 3] = v.w;
        }
        __syncthreads();
        const int q = t >> 7, k_loc = t & 63, h = (t >> 6) & 1;
        short8 v0, v1;
#pragma unroll
        for (int jj = 0; jj < 8; ++jj) {
            v0[jj] = (short)f2bf(tile[2 * (h * 16 + jj) + q][k_loc]);
            v1[jj] = (short)f2bf(tile[2 * (h * 16 + 8 + jj) + q][k_loc]);
        }
        long ob = (long)q * 524288 + (long)(k0 + k_loc) * 512 + (p0 >> 1) + h * 16;
        *(short8*)&gt[ob] = v0;
        *(short8*)&gt[ob + 8] = v1;
    }
}

// MFMA compute step over staged As/Bs (BK=128, row stride 128, 16 granules,
// XOR swizzle slot = granule ^ (row&15)). NW = wave-tile N count (4 or 2).
#define MFMA_TILE_STEP(As, Bs, NW)                                                  \
    {                                                                               \
        _Pragma("unroll")                                                           \
        for (int kk = 0; kk < 128; kk += 32) {                                      \
            const int gq = (kk >> 3) + (lane >> 4);                                 \
            const int slot = gq ^ (lane & 15);                                      \
            short8 af[4], bfr[NW];                                                  \
            _Pragma("unroll")                                                       \
            for (int i = 0; i < 4; ++i)                                             \
                af[i] = *(const short8*)&As[(wm + i * 16 + (lane & 15)) * 128 + slot * 8]; \
            _Pragma("unroll")                                                       \
            for (int j = 0; j < NW; ++j)                                            \
                bfr[j] = *(const short8*)&Bs[(wn + j * 16 + (lane & 15)) * 128 + slot * 8]; \
            _Pragma("unroll")                                                       \
            for (int i = 0; i < 4; ++i)                                             \
                _Pragma("unroll")                                                   \
                for (int j = 0; j < NW; ++j)                                        \
                    acc[i][j] = __builtin_amdgcn_mfma_f32_16x16x32_bf16(af[i], bfr[j], acc[i][j], 0, 0, 0); \
        }                                                                           \
    }

// ---- launch 2: E gemm (blocks 0..63) + SE MLP (blocks 64..79) -----------
// E_q[o,sp] = sum_i dwL[o,i]*gt[q][sp][i]   (M=512 o, N=1024 sp, K=512)
__global__ __launch_bounds__(256)
void k_we(const u16* __restrict__ dwb, const u16* __restrict__ gt,
          u16* __restrict__ Eb, const float* __restrict__ sm,
          const float* __restrict__ w1, const float* __restrict__ b1,
          const float* __restrict__ w2, const float* __restrict__ b2,
          float* __restrict__ y) {
    __shared__ __align__(16) u16 As[128 * 128];
    __shared__ __align__(16) u16 Bs[128 * 128];
    const int bx = blockIdx.x;
    const int tid = threadIdx.x;
    if (bx < 64) {
        const int q = bx >> 5, rem = bx & 31;
        const int m0 = (rem >> 3) * 128, n0 = (rem & 7) * 128;
        const u16* Bb = gt + (long)q * 524288;
        const int lane = tid & 63, wave = tid >> 6;
        const int wm = (wave >> 1) * 64, wn = (wave & 1) * 64;
        f32x4 acc[4][4];
#pragma unroll
        for (int i = 0; i < 4; ++i)
#pragma unroll
            for (int j = 0; j < 4; ++j) acc[i][j] = (f32x4){0.f, 0.f, 0.f, 0.f};
        int srow[8], sg8[8];
#pragma unroll
        for (int r = 0; r < 8; ++r) {
            int c = r * 256 + tid;
            srow[r] = c >> 4;
            sg8[r] = ((c & 15) ^ (srow[r] & 15)) * 8;
        }
        for (int k0 = 0; k0 < 512; k0 += 128) {
#pragma unroll
            for (int r = 0; r < 8; ++r) {
                const int c = r * 256 + tid;
                GLD16(dwb + (long)(m0 + srow[r]) * 1024 + (k0 + sg8[r]), &As[c * 8]);
                GLD16(Bb + (long)(n0 + srow[r]) * 512 + (k0 + sg8[r]), &Bs[c * 8]);
            }
            __syncthreads();
            MFMA_TILE_STEP(As, Bs, 4);
            __syncthreads();
        }
        const int col = lane & 15, rq = (lane >> 4) * 4;
#pragma unroll
        for (int i = 0; i < 4; ++i)
#pragma unroll
            for (int j = 0; j < 4; ++j)
#pragma unroll
                for (int r = 0; r < 4; ++r) {
                    int row = m0 + wm + i * 16 + rq + r;
                    int ncol = n0 + wn + j * 16 + col;
                    Eb[(long)q * 524288 + (long)row * 1024 + ncol] = f2bf(acc[i][j][r]);
                }
    } else {
        // SE MLP for batch b = bx - 64
        const int b = bx - 64;
        float* s_s = (float*)As;            // 512 floats
        float* s_y1 = (float*)Bs;           // 32 floats
        const int t = tid;
        s_s[t] = sm[b * NC + t];
        s_s[t + 256] = sm[b * NC + t + 256];
        __syncthreads();
        {
            const int r = t >> 3, sub = t & 7;
            const float4* wr = (const float4*)(w1 + r * NC + sub * 64);
            const float4* sv = (const float4*)(s_s + sub * 64);
            float acc = 0.f;
#pragma unroll
            for (int i = 0; i < 16; ++i) {
                float4 wv = wr[i];
                float4 s4 = sv[i];
                acc += wv.x * s4.x + wv.y * s4.y + wv.z * s4.z + wv.w * s4.w;
            }
            acc += __shfl_down(acc, 4);
            acc += __shfl_down(acc, 2);
            acc += __shfl_down(acc, 1);
            if (sub == 0) s_y1[r] = fmaxf(acc + b1[r], 0.0f);
        }
        __syncthreads();
        for (int i = 0; i < 2; ++i) {
            int c = t + i * 256;
            float acc = b2[c];
#pragma unroll
            for (int r = 0; r < NR; ++r) acc += s_y1[r] * w2[c * NR + r];
            y[b * NC + c] = 1.0f / (1.0f + expf(-acc));
        }
    }
}

// out32 = x*y -> bf16 [c,s] (o32), [s,c] (o32t), optional sigmoid [s,c].
__global__ void k_scale(const float* __restrict__ x, const float* __restrict__ y,
                        u16* __restrict__ o32, u16* __restrict__ o32t,
                        u16* __restrict__ sig_t) {
    const int b = blockIdx.z;
    const int c0 = blockIdx.y * 32;
    const int s0 = blockIdx.x * 32;
    const int tx = threadIdx.x & 31, ty = threadIdx.x >> 5;
    __shared__ float tile[32][33];
    const float* xb = x + (long)b * NC * NS;
#pragma unroll
    for (int it = 0; it < 4; ++it) {
        int c = c0 + ty + it * 8;
        float v = xb[(long)c * NS + s0 + tx] * y[b * NC + c];
        tile[ty + it * 8][tx] = v;
        o32[((long)b * NC + c) * NS + s0 + tx] = f2bf(v);
    }
    __syncthreads();
#pragma unroll
    for (int it = 0; it < 4; ++it) {
        int sr = ty + it * 8;
        float tv = tile[tx][sr];
        long idx = ((long)b * NS + (s0 + sr)) * NC + c0 + tx;
        o32t[idx] = f2bf(tv);
        if (sig_t) sig_t[idx] = f2bf(sigm(tv));
    }
}

// ------- patch attention: 8 x-positions per block, 512 threads -----------
// halo = 3 rows x 10 x-positions = 30 pairs. ONFLY: derive sigmoid during
// staging (used when workspace can't hold sig_t). OOB entries are 0 (the
// reference pads AFTER sigmoid).
template <bool ONFLY>
__global__ __launch_bounds__(512)
void k_attn(const u16* __restrict__ sig_t, const u16* __restrict__ o32t,
            u16* __restrict__ g2) {
    const int wave = threadIdx.x >> 6, lane = threadIdx.x & 63;
    const int tid = threadIdx.x;
    const int bx = blockIdx.x;                   // 128 blocks/batch: 4 per row
    const int b = blockIdx.y;
    const int y0 = bx >> 2;
    const int xbase = (bx & 3) * 8;
    const long base = (long)b * NS * NC;
    __shared__ __align__(16) u16 smem[2 * 30 * NC];   // sig: 0..29, raw: 30..59

#pragma unroll
    for (int it = 0; it < 4; ++it) {
        int idx = it * 512 + tid;                 // 1920 chunks total
        if (idx < 30 * 64) {
            int pair = idx >> 6;                  // 0..29, wave-uniform
            int ch0 = (idx & 63) * 8;
            int prow = pair / 10;
            int pxc = pair - prow * 10;
            int yy = y0 + prow - 1;
            int xx = xbase + pxc - 1;
            short8 rv = (short8){0, 0, 0, 0, 0, 0, 0, 0};
            short8 sv = (short8){0, 0, 0, 0, 0, 0, 0, 0};
            if (yy >= 0 && yy < 32 && xx >= 0 && xx < 32) {
                long roff = base + (long)(yy * 32 + xx) * NC + ch0;
                rv = *(const short8*)&o32t[roff];
                if (ONFLY) {
#pragma unroll
                    for (int j = 0; j < 8; ++j) sv[j] = (short)f2bf(sigm(bf2f((u16)rv[j])));
                } else {
                    sv = *(const short8*)&sig_t[roff];
                }
            }
            *(short8*)&smem[pair * NC + ch0] = sv;
            *(short8*)&smem[(30 + pair) * NC + ch0] = rv;
        }
    }
    __syncthreads();

    const int coff = lane * 8;
    short8 csv = *(const short8*)&smem[(11 + wave) * NC + coff];   // own sig
    float sc[8];
#pragma unroll
    for (int j = 0; j < 8; ++j) sc[j] = bf2f((u16)csv[j]);

    float part[9];
#pragma unroll
    for (int k = 0; k < 9; ++k) {
        int pair = (k / 3) * 10 + wave + k % 3;
        short8 sv = *(const short8*)&smem[pair * NC + coff];
        float p = 0.f;
#pragma unroll
        for (int j = 0; j < 8; ++j) p += sc[j] * bf2f((u16)sv[j]);
        part[k] = p;
    }
#pragma unroll
    for (int k = 0; k < 9; ++k)
        for (int off = 32; off; off >>= 1) part[k] += __shfl_down(part[k], off);

    if (lane == 0) {
        float mx = -1e30f;
#pragma unroll
        for (int k = 0; k < 9; ++k) { part[k] *= (1.0f / 512.0f); mx = fmaxf(mx, part[k]); }
        float sum = 0.f;
#pragma unroll
        for (int k = 0; k < 9; ++k) { part[k] = __expf(part[k] - mx); sum += part[k]; }
        float inv = 1.0f / sum;
#pragma unroll
        for (int k = 0; k < 9; ++k) part[k] *= inv;
    }
    float g[8] = {0.f, 0.f, 0.f, 0.f, 0.f, 0.f, 0.f, 0.f};
#pragma unroll
    for (int k = 0; k < 9; ++k) {
        float a = __shfl(part[k], 0);
        int pair = (k / 3) * 10 + wave + k % 3;
        short8 rv = *(const short8*)&smem[(30 + pair) * NC + coff];
#pragma unroll
        for (int j = 0; j < 8; ++j) g[j] += a * bf2f((u16)rv[j]);
    }
    short8 ov;
#pragma unroll
    for (int j = 0; j < 8; ++j) ov[j] = (short)f2bf(g[j]);
    const int s = y0 * 32 + xbase + wave;
    *(short8*)&g2[base + (long)s * NC + coff] = ov;
}

// ---- g2b [b][p][c] -> g2sep[b][q][c][j] = g2b[b][2j+q][c] ---------------
__global__ __launch_bounds__(256)
void k_tr2(const u16* __restrict__ g2, u16* __restrict__ gs) {
    const int b = blockIdx.y;
    const int c0 = (blockIdx.x & 7) * 64;
    const int j0 = ((blockIdx.x >> 3) & 7) * 64;
    const int q = blockIdx.x >> 6;
    const int t = threadIdx.x;
    __shared__ __align__(16) u16 tile[64 * 64];       // 8 KB
    const u16* src = g2 + (long)b * 524288 + (long)(2 * j0 + q) * 512 + c0;
#pragma unroll
    for (int it = 0; it < 2; ++it) {
        int c = it * 256 + t;
        int jl = c >> 3, sg = c & 7;
        short8 v = *(const short8*)&src[(long)jl * 1024 + sg * 8];
        int slot = sg ^ ((jl >> 3) & 7);
        *(short8*)&tile[jl * 64 + slot * 8] = v;
    }
    __syncthreads();
#pragma unroll
    for (int it = 0; it < 2; ++it) {
        int c = it * 256 + t;
        int cl = c >> 3, jg = c & 7;
        const int gcs = cl >> 3, co = cl & 7;
        short8 v;
#pragma unroll
        for (int jj = 0; jj < 8; ++jj) {
            int j = jg * 8 + jj;
            int slot = gcs ^ jg;                       // (j>>3)&7 == jg
            v[jj] = (short)tile[j * 64 + slot * 8 + co];
        }
        *(short8*)&gs[(long)b * 524288 + (long)q * 262144 +
                      (long)(c0 + cl) * 512 + j0 + jg * 8] = v;
    }
}

// ---- fused Z GEMM: Z[o, band*512+r] = sum_{sp<1024} E_band[o,sp]*o32[b,r,sp]
//                                     + sum_{j<512} dwR[o,j]*g2sep[b,band,r,j]
// BK=128, 128x128 tile, 512 threads / 8 waves (wave tile 64x32):
// LDS 64 KB -> 2 blocks/CU -> 16 waves/CU (vs 8 at 256 threads) — attacks
// the measured occupancy limit (19%) without changing schedule or traffic.
__global__ __launch_bounds__(512)
void k_zgemm(const u16* __restrict__ Em, const u16* __restrict__ dwb,
             const u16* __restrict__ o32, const u16* __restrict__ gsep,
             u16* __restrict__ Z) {
    const int b = blockIdx.z;
    const int band = blockIdx.y & 1;
    const int m0 = (blockIdx.y >> 1) * 128;      // o
    const int n0 = blockIdx.x * 128;             // r
    __shared__ __align__(16) u16 As[128 * 128];  // 32 KB
    __shared__ __align__(16) u16 Bs[128 * 128];  // 32 KB
    const int tid = threadIdx.x;                 // 0..511
    const int lane = tid & 63, wave = tid >> 6;  // 8 waves
    const int wm = (wave >> 2) * 64, wn = (wave & 3) * 32;
    f32x4 acc[4][2];
#pragma unroll
    for (int i = 0; i < 4; ++i)
#pragma unroll
        for (int j = 0; j < 2; ++j) acc[i][j] = (f32x4){0.f, 0.f, 0.f, 0.f};

    const u16* A0 = Em + (long)band * 524288 + (long)m0 * 1024;     // stride 1024
    const u16* B0 = o32 + (long)b * 524288 + (long)n0 * 1024;       // stride 1024
    const u16* A1 = dwb + 512 + (long)m0 * 1024;                    // stride 1024
    const u16* B1 = gsep + (long)b * 524288 + (long)band * 262144 + (long)n0 * 512;

    // staging: 2048 chunks per operand, 4 per thread;
    // chunk c -> row c>>4, slot c&15, source granule (c&15)^(row&15).
#define ZSTAGE(k0, Abase, Bbase, ldb)                                         \
    {                                                                         \
        _Pragma("unroll")                                                     \
        for (int r = 0; r < 4; ++r) {                                         \
            const int c = r * 512 + tid;                                      \
            const int srow = c >> 4;                                          \
            const int sg = ((c & 15) ^ (srow & 15)) * 8;                      \
            GLD16((Abase) + (long)srow * 1024 + (k0 + sg), &As[c * 8]);       \
            GLD16((Bbase) + (long)srow * (ldb) + (k0 + sg), &Bs[c * 8]);      \
        }                                                                     \
    }

    for (int k0 = 0; k0 < 1024; k0 += 128) {
        ZSTAGE(k0, A0, B0, 1024);
        __syncthreads();
        MFMA_TILE_STEP(As, Bs, 2);
        __syncthreads();
    }
    for (int k0 = 0; k0 < 512; k0 += 128) {
        ZSTAGE(k0, A1, B1, 512);
        __syncthreads();
        MFMA_TILE_STEP(As, Bs, 2);
        __syncthreads();
    }
#undef ZSTAGE
    const int col = lane & 15, rq = (lane >> 4) * 4;
#pragma unroll
    for (int i = 0; i < 4; ++i)
#pragma unroll
        for (int j = 0; j < 2; ++j)
#pragma unroll
            for (int r = 0; r < 4; ++r) {
                int row = m0 + wm + i * 16 + rq + r;
                int ncol = n0 + wn + j * 16 + col;
                Z[((long)b * 512 + row) * 1024 + band * 512 + ncol] = f2bf(acc[i][j][r]);
            }
}

// -- InstanceNorm over s (1024) + LeakyReLU(0.2), per (b,o) row, bf16 in --
__global__ void k_norm(const u16* __restrict__ z, float* __restrict__ out) {
    const int row = blockIdx.x;
    const int t = threadIdx.x;
    uint2 u = ((const uint2*)(z + (long)row * NS))[t];
    float v0 = bf2f((u16)(u.x & 0xffffu)), v1 = bf2f((u16)(u.x >> 16));
    float v2 = bf2f((u16)(u.y & 0xffffu)), v3 = bf2f((u16)(u.y >> 16));
    float sm = v0 + v1 + v2 + v3;
    float sq = v0 * v0 + v1 * v1 + v2 * v2 + v3 * v3;
    for (int off = 32; off; off >>= 1) { sm += __shfl_down(sm, off); sq += __shfl_down(sq, off); }
    __shared__ __align__(16) float rs[4], rq2[4];
    if ((t & 63) == 0) { rs[t >> 6] = sm; rq2[t >> 6] = sq; }
    __syncthreads();
    float tot = rs[0] + rs[1] + rs[2] + rs[3];
    float totq = rq2[0] + rq2[1] + rq2[2] + rq2[3];
    float mu = tot * (1.0f / 1024.0f);
    float var = totq * (1.0f / 1024.0f) - mu * mu;
    float sc = rsqrtf(var + 1e-5f);
    float4 o;
    float a;
    a = (v0 - mu) * sc; o.x = (a >= 0.f) ? a : 0.2f * a;
    a = (v1 - mu) * sc; o.y = (a >= 0.f) ? a : 0.2f * a;
    a = (v2 - mu) * sc; o.z = (a >= 0.f) ? a : 0.2f * a;
    a = (v3 - mu) * sc; o.w = (a >= 0.f) ? a : 0.2f * a;
    ((float4*)(out + (long)row * NS))[t] = o;
}

extern "C" void kernel_launch(void* const* d_in, const int* in_sizes, int n_in,
                              void* d_out, int out_size, void* d_ws, size_t ws_size,
                              hipStream_t stream) {
    const float* x   = (const float*)d_in[0];
    const float* w1  = (const float*)d_in[1];
    const float* b1  = (const float*)d_in[2];
    const float* w2  = (const float*)d_in[3];
    const float* b2  = (const float*)d_in[4];
    const float* dw  = (const float*)d_in[5];
    const float* gus = (const float*)d_in[6];
    float* out = (float*)d_out;
    char* ws = (char*)d_ws;

    // layout: head 5.1 MB | o32 16 | o32t 16 | [sig_t 16] | g2b 16
    // g2sep (16) overlays o32t (dead after attn); Z (16) overlays g2b slot.
    float* sm_buf = (float*)(ws + 0);                    // 32 KB
    float* y_buf  = (float*)(ws + 32768);                // 32 KB
    u16* dwbf     = (u16*)(ws + 65536);                  // 1 MB  [512][1024]
    u16* gusTb    = (u16*)(ws + 1114112);                // 2 MB  [2][1024][512]
    u16* Ebuf     = (u16*)(ws + 3211264);                // 2 MB  [2][512][1024]
    u16* o32      = (u16*)(ws + 5308416);                // 16 MB [b][c][s]
    u16* o32t     = (u16*)(ws + 22085632);               // 16 MB [b][s][c]
    const bool big = (ws_size >= 72417280UL);
    u16* sig_t    = big ? (u16*)(ws + 38862848) : (u16*)0;   // 16 MB (optional)
    u16* g2b      = big ? (u16*)(ws + 55640064) : (u16*)(ws + 38862848);
    u16* g2sep    = (u16*)(ws + 22085632);               // over o32t
    u16* Z        = g2b;                                 // over g2b slot

    // L1: mean + dw cvt + gusT (independent)
    k_pre<<<dim3(NB * NC + 2048 + 256), dim3(256), 0, stream>>>(
        x, sm_buf, dw, dwbf, gus, gusTb);
    // L2: E gemm + SE MLP (both depend only on L1)
    k_we<<<dim3(80), dim3(256), 0, stream>>>(
        dwbf, gusTb, Ebuf, sm_buf, w1, b1, w2, b2, y_buf);
    // L3: scale (+ sigmoid materialization when workspace allows)
    k_scale<<<dim3(32, 16, NB), dim3(256), 0, stream>>>(x, y_buf, o32, o32t, sig_t);
    // L4: attn (o32t [+sig_t] dead after this)
    if (big)
        k_attn<false><<<dim3(128, NB), dim3(512), 0, stream>>>(sig_t, o32t, g2b);
    else
        k_attn<true><<<dim3(128, NB), dim3(512), 0, stream>>>(sig_t, o32t, g2b);
    // L5: band-deinterleave g2 (o32t slot -> g2sep)
    k_tr2<<<dim3(128, NB), dim3(256), 0, stream>>>(g2b, g2sep);
    // L6: fused Z GEMM (writes Z over g2b slot; reads of g2sep disjoint)
    k_zgemm<<<dim3(4, 8, NB), dim3(512), 0, stream>>>(Ebuf, dwbf, o32, g2sep, Z);
    // L7: instance norm + leaky relu
    k_norm<<<dim3(NB * NC), dim3(256), 0, stream>>>(Z, out);
}